// Round 1
// baseline (70.423 us; speedup 1.0000x reference)
//
#include <hip/hip_runtime.h>

typedef __attribute__((ext_vector_type(4))) float f32x4;
typedef __attribute__((ext_vector_type(8))) short bf16x8;

#define MFMA(a, b, c) __builtin_amdgcn_mfma_f32_16x16x32_bf16((a), (b), (c), 0, 0, 0)

__device__ __forceinline__ unsigned short f2bf(float x) {
    unsigned u = __builtin_bit_cast(unsigned, x);
    unsigned r = u + 0x7fffu + ((u >> 16) & 1u);
    return (unsigned short)(r >> 16);
}
__device__ __forceinline__ float bf2f(unsigned short h) {
    return __builtin_bit_cast(float, (unsigned)h << 16);
}

// Stage a 64x64 f32 tile (row-major, stride 64) into hi/lo bf16 LDS tiles,
// XOR-swizzled: byte_off = (row*128 + col*2) ^ ((row&7)<<4).
__device__ __forceinline__ void stage_rm(const float* __restrict__ src,
                                         char* hi_t, char* lo_t, float scale) {
    const int tid = threadIdx.x;
    const int row = tid >> 2;
    const int c0  = (tid & 3) << 4;
    const float* p = src + row * 64 + c0;
    f32x4 vv[4];
    vv[0] = *(const f32x4*)(p + 0);
    vv[1] = *(const f32x4*)(p + 4);
    vv[2] = *(const f32x4*)(p + 8);
    vv[3] = *(const f32x4*)(p + 12);
    bf16x8 h2[2], l2[2];
#pragma unroll
    for (int e = 0; e < 16; ++e) {
        float x = vv[e >> 2][e & 3] * scale;
        unsigned short hb = f2bf(x);
        unsigned short lb = f2bf(x - bf2f(hb));
        h2[e >> 3][e & 7] = (short)hb;
        l2[e >> 3][e & 7] = (short)lb;
    }
#pragma unroll
    for (int gi = 0; gi < 2; ++gi) {
        int off = (row * 128 + (c0 + gi * 8) * 2) ^ ((row & 7) << 4);
        *(bf16x8*)(hi_t + off) = h2[gi];
        *(bf16x8*)(lo_t + off) = l2[gi];
    }
}

// Stage a 64x64 f32 tile transposed: LDS[d][t] from src[t][d], hi/lo, same swizzle.
__device__ __forceinline__ void stage_tr(const float* __restrict__ src,
                                         char* hi_t, char* lo_t) {
    const int tid = threadIdx.x;
    const int t  = tid >> 2;
    const int c0 = (tid & 3) << 4;
    const float* p = src + t * 64 + c0;
    f32x4 vv[4];
    vv[0] = *(const f32x4*)(p + 0);
    vv[1] = *(const f32x4*)(p + 4);
    vv[2] = *(const f32x4*)(p + 8);
    vv[3] = *(const f32x4*)(p + 12);
#pragma unroll
    for (int e = 0; e < 16; ++e) {
        float x = vv[e >> 2][e & 3];
        unsigned short hb = f2bf(x);
        unsigned short lb = f2bf(x - bf2f(hb));
        int d = c0 + e;
        int off = (d * 128 + t * 2) ^ ((d & 7) << 4);
        *(unsigned short*)(hi_t + off) = hb;
        *(unsigned short*)(lo_t + off) = lb;
    }
}

// Read an 8-element (16B) MFMA fragment: row (l16 + 16*tile), 8 consecutive cols.
__device__ __forceinline__ bf16x8 ld_frag(const char* tile, int row, int col) {
    int off = (row * 128 + col * 2) ^ ((row & 7) << 4);
    return *(const bf16x8*)(tile + off);
}

__global__ __launch_bounds__(256) void bigbird_kernel(
    const float* __restrict__ Q, const float* __restrict__ K,
    const float* __restrict__ V, const float* __restrict__ M,
    float* __restrict__ Out) {
    constexpr int H = 16, F = 1024, T = 1024, D = 64;

    __shared__ char kq_hi[8192];
    __shared__ char kq_lo[8192];
    __shared__ char vt_hi[8192];
    __shared__ char vt_lo[8192];
    __shared__ char p_sm[8192];
    __shared__ int flags[16];

    const int bid = blockIdx.x;
    const int fb  = bid & 15;
    const int h   = (bid >> 4) & 15;
    const int b   = bid >> 8;
    const int tid  = threadIdx.x;
    const int lane = tid & 63;
    const int w    = tid >> 6;
    const int g    = lane >> 4;
    const int l16  = lane & 15;

    // Block-level mask flags: mask is constant on 64x64 blocks by construction.
    if (tid < 16)
        flags[tid] = (M[(h * 1024 + fb * 64) * 1024 + tid * 64] > 0.5f) ? 1 : 0;

    // Stage Q (scaled by 1/sqrt(D)=0.125) into the K tile buffers, grab frags.
    const float* qb = Q + ((size_t)(b * H + h) * F + fb * 64) * D;
    stage_rm(qb, kq_hi, kq_lo, 0.125f);
    __syncthreads();

    bf16x8 qh[2], ql[2];
#pragma unroll
    for (int kk = 0; kk < 2; ++kk) {
        qh[kk] = ld_frag(kq_hi, w * 16 + l16, kk * 32 + g * 8);
        ql[kk] = ld_frag(kq_lo, w * 16 + l16, kk * 32 + g * 8);
    }

    f32x4 acc[4];
    float m_r[4], l_r[4];
#pragma unroll
    for (int j = 0; j < 4; ++j) acc[j] = f32x4{0.f, 0.f, 0.f, 0.f};
#pragma unroll
    for (int r = 0; r < 4; ++r) { m_r[r] = -1e30f; l_r[r] = 0.f; }

    const float* kb = K + (size_t)(b * H + h) * T * D;
    const float* vb = V + (size_t)(b * H + h) * T * D;

    for (int tb = 0; tb < 16; ++tb) {
        if (!flags[tb]) continue;          // wave-uniform
        __syncthreads();                   // prior readers of k/v/p tiles done
        stage_rm(kb + tb * 64 * D, kq_hi, kq_lo, 1.0f);
        stage_tr(vb + tb * 64 * D, vt_hi, vt_lo);
        __syncthreads();

        // S = Q K^T  (error-compensated: hh + hl + lh)
        f32x4 s[4];
#pragma unroll
        for (int j = 0; j < 4; ++j) {
            s[j] = f32x4{0.f, 0.f, 0.f, 0.f};
#pragma unroll
            for (int kk = 0; kk < 2; ++kk) {
                bf16x8 bh = ld_frag(kq_hi, j * 16 + l16, kk * 32 + g * 8);
                bf16x8 bl = ld_frag(kq_lo, j * 16 + l16, kk * 32 + g * 8);
                s[j] = MFMA(qh[kk], bh, s[j]);
                s[j] = MFMA(qh[kk], bl, s[j]);
                s[j] = MFMA(ql[kk], bh, s[j]);
            }
        }

        // Online softmax. C-layout: lane holds rows g*4+r, col j*16+l16.
        float rmax[4];
#pragma unroll
        for (int r = 0; r < 4; ++r)
            rmax[r] = fmaxf(fmaxf(s[0][r], s[1][r]), fmaxf(s[2][r], s[3][r]));
#pragma unroll
        for (int off = 1; off < 16; off <<= 1) {
#pragma unroll
            for (int r = 0; r < 4; ++r)
                rmax[r] = fmaxf(rmax[r], __shfl_xor(rmax[r], off, 64));
        }
        float alpha[4], psum[4];
#pragma unroll
        for (int r = 0; r < 4; ++r) {
            float mn = fmaxf(m_r[r], rmax[r]);
            alpha[r] = __expf(m_r[r] - mn);
            m_r[r]   = mn;
            psum[r]  = 0.f;
        }
#pragma unroll
        for (int j = 0; j < 4; ++j) {
#pragma unroll
            for (int r = 0; r < 4; ++r) {
                float pe = __expf(s[j][r] - m_r[r]);
                s[j][r] = pe;
                psum[r] += pe;
            }
        }
#pragma unroll
        for (int off = 1; off < 16; off <<= 1) {
#pragma unroll
            for (int r = 0; r < 4; ++r)
                psum[r] += __shfl_xor(psum[r], off, 64);
        }
#pragma unroll
        for (int r = 0; r < 4; ++r)
            l_r[r] = l_r[r] * alpha[r] + psum[r];
#pragma unroll
        for (int j = 0; j < 4; ++j)
#pragma unroll
            for (int r = 0; r < 4; ++r)
                acc[j][r] *= alpha[r];

        // P -> LDS (bf16) to reshape C-layout into A-fragment layout.
#pragma unroll
        for (int j = 0; j < 4; ++j) {
#pragma unroll
            for (int r = 0; r < 4; ++r) {
                int row = w * 16 + g * 4 + r;
                int col = j * 16 + l16;
                int off = (row * 128 + col * 2) ^ ((row & 7) << 4);
                *(unsigned short*)(p_sm + off) = f2bf(s[j][r]);
            }
        }
        __syncthreads();

        // O += P * V  (V error-compensated hi/lo; P single bf16)
#pragma unroll
        for (int kk = 0; kk < 2; ++kk) {
            bf16x8 pa = ld_frag(p_sm, w * 16 + l16, kk * 32 + g * 8);
#pragma unroll
            for (int jd = 0; jd < 4; ++jd) {
                bf16x8 vh = ld_frag(vt_hi, jd * 16 + l16, kk * 32 + g * 8);
                bf16x8 vl = ld_frag(vt_lo, jd * 16 + l16, kk * 32 + g * 8);
                acc[jd] = MFMA(pa, vh, acc[jd]);
                acc[jd] = MFMA(pa, vl, acc[jd]);
            }
        }
    }

    // Epilogue: normalize and write out [B, F, H, D].
#pragma unroll
    for (int r = 0; r < 4; ++r) {
        float inv = 1.0f / l_r[r];
        int f = fb * 64 + w * 16 + g * 4 + r;
        float* ob = Out + ((size_t)(b * F + f) * H + h) * D;
#pragma unroll
        for (int jd = 0; jd < 4; ++jd)
            ob[jd * 16 + l16] = acc[jd][r] * inv;
    }
}

extern "C" void kernel_launch(void* const* d_in, const int* in_sizes, int n_in,
                              void* d_out, int out_size, void* d_ws, size_t ws_size,
                              hipStream_t stream) {
    const float* q = (const float*)d_in[0];
    const float* k = (const float*)d_in[1];
    const float* v = (const float*)d_in[2];
    const float* m = (const float*)d_in[3];
    float* out = (float*)d_out;
    bigbird_kernel<<<dim3(512), dim3(256), 0, stream>>>(q, k, v, m, out);
}

// Round 2
// 60.619 us; speedup vs baseline: 1.1617x; 1.1617x over previous
//
#include <hip/hip_runtime.h>

typedef __attribute__((ext_vector_type(4))) float f32x4;
typedef __attribute__((ext_vector_type(8))) short bf16x8;

#define MFMA(a, b, c) __builtin_amdgcn_mfma_f32_16x16x32_bf16((a), (b), (c), 0, 0, 0)

constexpr size_t TILE_BYTES = 8192;          // 64x64 bf16
constexpr size_t NTILES     = 512;           // B*H*16
constexpr size_t ARR_S      = NTILES * TILE_BYTES;   // 4 MiB per array
constexpr size_t WS_NEED    = 4 * ARR_S;             // Kh, Kl, Vh, Vl

// RNE f32->bf16 (used for P only; K/V/Q use compensated truncation split)
__device__ __forceinline__ unsigned short f2bf(float x) {
    unsigned u = __builtin_bit_cast(unsigned, x);
    unsigned r = u + 0x7fffu + ((u >> 16) & 1u);
    return (unsigned short)(r >> 16);
}
__device__ __forceinline__ float bf2f(unsigned short h) {
    return __builtin_bit_cast(float, (unsigned)h << 16);
}
// Truncation hi/lo split: hi = x&0xFFFF0000, lo = trunc(x - hi). Residual ~2^-16.
__device__ __forceinline__ void split_tr(float x, short& hi, short& lo) {
    unsigned u = __builtin_bit_cast(unsigned, x);
    unsigned hu = u & 0xFFFF0000u;
    float rem = x - __builtin_bit_cast(float, hu);
    hi = (short)(hu >> 16);
    lo = (short)(__builtin_bit_cast(unsigned, rem) >> 16);
}
// Swizzled byte offset inside an 8 KiB 64x64 bf16 tile (row stride 128 B).
__device__ __forceinline__ int swz_off(int row, int col) {
    return (row * 128 + col * 2) ^ ((row & 7) << 4);
}
__device__ __forceinline__ bf16x8 ld_frag(const char* tile, int row, int col) {
    return *(const bf16x8*)(tile + swz_off(row, col));
}

// ---------------------------------------------------------------------------
// Pre-pass: K -> (Kh,Kl) row-major swizzled tiles; V -> (Vh,Vl) transposed
// swizzled tiles. One WG per (b,h,tb) tile. Output bytes are the exact LDS
// image so the main kernel can global_load_lds them linearly.
// ---------------------------------------------------------------------------
__global__ __launch_bounds__(256) void bigbird_prepass(
    const float* __restrict__ K, const float* __restrict__ V,
    char* __restrict__ ws) {
    __shared__ float vt[64][65];
    const int tile = blockIdx.x;
    const int tid  = threadIdx.x;
    const int row  = tid >> 2;          // 0..63
    const int c0   = (tid & 3) << 4;    // 0,16,32,48
    const float* Kt = K + (size_t)tile * 4096;
    const float* Vt = V + (size_t)tile * 4096;
    char* Kh = ws + (size_t)tile * TILE_BYTES;
    char* Kl = Kh + ARR_S;
    char* Vh = Kh + 2 * ARR_S;
    char* Vl = Kh + 3 * ARR_S;

    {   // K: rows coalesced
        const float* p = Kt + row * 64 + c0;
        f32x4 vv[4] = { *(const f32x4*)(p), *(const f32x4*)(p + 4),
                        *(const f32x4*)(p + 8), *(const f32x4*)(p + 12) };
        bf16x8 hh[2], ll[2];
#pragma unroll
        for (int e = 0; e < 16; ++e) {
            short hi, lo;
            split_tr(vv[e >> 2][e & 3], hi, lo);
            hh[e >> 3][e & 7] = hi;
            ll[e >> 3][e & 7] = lo;
        }
#pragma unroll
        for (int gi = 0; gi < 2; ++gi) {
            int off = swz_off(row, c0 + gi * 8);
            *(bf16x8*)(Kh + off) = hh[gi];
            *(bf16x8*)(Kl + off) = ll[gi];
        }
    }
    {   // V: coalesced load into padded LDS for transpose
        const float* p = Vt + row * 64 + c0;
        f32x4 vv[4] = { *(const f32x4*)(p), *(const f32x4*)(p + 4),
                        *(const f32x4*)(p + 8), *(const f32x4*)(p + 12) };
#pragma unroll
        for (int e = 0; e < 16; ++e) vt[row][c0 + e] = vv[e >> 2][e & 3];
    }
    __syncthreads();
    {   // transposed gather (2-way, conflict-free w/ pad): V^T[d=row][t=c0+e]
        bf16x8 hh[2], ll[2];
#pragma unroll
        for (int e = 0; e < 16; ++e) {
            short hi, lo;
            split_tr(vt[c0 + e][row], hi, lo);
            hh[e >> 3][e & 7] = hi;
            ll[e >> 3][e & 7] = lo;
        }
#pragma unroll
        for (int gi = 0; gi < 2; ++gi) {
            int off = swz_off(row, c0 + gi * 8);
            *(bf16x8*)(Vh + off) = hh[gi];
            *(bf16x8*)(Vl + off) = ll[gi];
        }
    }
}

// ---------------------------------------------------------------------------
// Main kernel: flash-style over unmasked 64x64 col-blocks, double-buffered
// global_load_lds staging of pre-converted tiles.
// ---------------------------------------------------------------------------
__global__ __launch_bounds__(256) void bigbird_main(
    const float* __restrict__ Q, const float* __restrict__ M,
    const char* __restrict__ ws, float* __restrict__ Out) {
    constexpr int H = 16, F = 1024, D = 64;

    __shared__ char tiles[2][4][8192];   // [buf][Kh,Kl,Vh,Vl]
    __shared__ char p_sm[8192];          // per-wave-private 16-row strips
    __shared__ int flags[16];
    __shared__ int list[16];
    __shared__ int ncnt;

    const int bid = blockIdx.x;
    const int fb  = bid & 15;
    const int h   = (bid >> 4) & 15;
    const int b   = bid >> 8;
    const int bh  = b * H + h;
    const int tid  = threadIdx.x;
    const int lane = tid & 63;
    const int w    = tid >> 6;
    const int g    = lane >> 4;
    const int l16  = lane & 15;

    if (tid < 16)
        flags[tid] = (M[((size_t)(h * 1024 + fb * 64)) * 1024 + tid * 64] > 0.5f) ? 1 : 0;

    // Q fragments straight from global into registers (scaled by 1/8).
    bf16x8 qh[2], ql[2];
    {
        const float* qr = Q + ((size_t)bh * F + fb * 64 + w * 16 + l16) * D;
#pragma unroll
        for (int kk = 0; kk < 2; ++kk) {
            const float* p = qr + kk * 32 + g * 8;
            f32x4 a = *(const f32x4*)p;
            f32x4 c = *(const f32x4*)(p + 4);
#pragma unroll
            for (int e = 0; e < 8; ++e) {
                float x = (e < 4 ? a[e] : c[e - 4]) * 0.125f;
                short hi, lo;
                split_tr(x, hi, lo);
                qh[kk][e] = hi;
                ql[kk][e] = lo;
            }
        }
    }
    __syncthreads();
    if (tid == 0) {
        int nn = 0;
        for (int t = 0; t < 16; ++t)
            if (flags[t]) list[nn++] = t;
        ncnt = nn;
    }
    __syncthreads();
    const int n = ncnt;

    f32x4 acc[4];
    float m_r[4], l_r[4];
#pragma unroll
    for (int j = 0; j < 4; ++j) acc[j] = f32x4{0.f, 0.f, 0.f, 0.f};
#pragma unroll
    for (int r = 0; r < 4; ++r) { m_r[r] = -1e30f; l_r[r] = 0.f; }

    const char* wsbh = ws + (size_t)bh * 16 * TILE_BYTES;

    // Wave w DMA-stages array w (Kh/Kl/Vh/Vl): 8 x 1 KiB chunks.
    auto stage = [&](int bufi, int tb) {
        const char* gt = wsbh + (size_t)tb * TILE_BYTES + (size_t)w * ARR_S;
        char* lt = tiles[bufi][w];
#pragma unroll
        for (int c = 0; c < 8; ++c)
            __builtin_amdgcn_global_load_lds(
                (const __attribute__((address_space(1))) void*)(gt + c * 1024 + lane * 16),
                (__attribute__((address_space(3))) void*)(lt + c * 1024), 16, 0, 0);
    };

    if (n > 0) stage(0, list[0]);

    for (int i = 0; i < n; ++i) {
        __syncthreads();   // vmcnt(0) drain: buf[i&1] staged; joins all waves
        if (i + 1 < n) stage((i + 1) & 1, list[i + 1]);   // overlaps compute
        const char* Kh = tiles[i & 1][0];
        const char* Kl = tiles[i & 1][1];
        const char* Vh = tiles[i & 1][2];
        const char* Vl = tiles[i & 1][3];

        // S = Q K^T (hh + hl + lh)
        f32x4 s[4];
#pragma unroll
        for (int j = 0; j < 4; ++j) {
            s[j] = f32x4{0.f, 0.f, 0.f, 0.f};
#pragma unroll
            for (int kk = 0; kk < 2; ++kk) {
                bf16x8 bhf = ld_frag(Kh, j * 16 + l16, kk * 32 + g * 8);
                bf16x8 blf = ld_frag(Kl, j * 16 + l16, kk * 32 + g * 8);
                s[j] = MFMA(qh[kk], bhf, s[j]);
                s[j] = MFMA(qh[kk], blf, s[j]);
                s[j] = MFMA(ql[kk], bhf, s[j]);
            }
        }

        // Online softmax; C-layout: lane holds rows g*4+r (+w*16), col j*16+l16.
        float rmax[4];
#pragma unroll
        for (int r = 0; r < 4; ++r)
            rmax[r] = fmaxf(fmaxf(s[0][r], s[1][r]), fmaxf(s[2][r], s[3][r]));
#pragma unroll
        for (int off = 1; off < 16; off <<= 1)
#pragma unroll
            for (int r = 0; r < 4; ++r)
                rmax[r] = fmaxf(rmax[r], __shfl_xor(rmax[r], off, 64));
        float alpha[4], psum[4];
#pragma unroll
        for (int r = 0; r < 4; ++r) {
            float mn = fmaxf(m_r[r], rmax[r]);
            alpha[r] = __expf(m_r[r] - mn);
            m_r[r]   = mn;
            psum[r]  = 0.f;
        }
#pragma unroll
        for (int j = 0; j < 4; ++j)
#pragma unroll
            for (int r = 0; r < 4; ++r) {
                float pe = __expf(s[j][r] - m_r[r]);
                s[j][r] = pe;
                psum[r] += pe;
            }
#pragma unroll
        for (int off = 1; off < 16; off <<= 1)
#pragma unroll
            for (int r = 0; r < 4; ++r)
                psum[r] += __shfl_xor(psum[r], off, 64);
#pragma unroll
        for (int r = 0; r < 4; ++r)
            l_r[r] = l_r[r] * alpha[r] + psum[r];
#pragma unroll
        for (int j = 0; j < 4; ++j)
#pragma unroll
            for (int r = 0; r < 4; ++r)
                acc[j][r] *= alpha[r];

        // P (bf16, RNE) -> wave-private LDS strip to reshape into A-frag.
#pragma unroll
        for (int j = 0; j < 4; ++j)
#pragma unroll
            for (int r = 0; r < 4; ++r) {
                int row = w * 16 + g * 4 + r;
                *(unsigned short*)(p_sm + swz_off(row, j * 16 + l16)) = f2bf(s[j][r]);
            }
        // Wave-local: wait own ds_writes (lgkm only; leaves prefetch vmcnt alone)
        asm volatile("s_waitcnt lgkmcnt(0)" ::: "memory");
        __builtin_amdgcn_sched_barrier(0);

        // O += P * V   (V hi/lo compensated)
#pragma unroll
        for (int kk = 0; kk < 2; ++kk) {
            bf16x8 pa = ld_frag(p_sm, w * 16 + l16, kk * 32 + g * 8);
#pragma unroll
            for (int jd = 0; jd < 4; ++jd) {
                bf16x8 vh = ld_frag(Vh, jd * 16 + l16, kk * 32 + g * 8);
                bf16x8 vl = ld_frag(Vl, jd * 16 + l16, kk * 32 + g * 8);
                acc[jd] = MFMA(pa, vh, acc[jd]);
                acc[jd] = MFMA(pa, vl, acc[jd]);
            }
        }
    }

    // Epilogue: normalize, write [B, F, H, D].
#pragma unroll
    for (int r = 0; r < 4; ++r) {
        float inv = 1.0f / l_r[r];
        int f = fb * 64 + w * 16 + g * 4 + r;
        float* ob = Out + ((size_t)(b * F + f) * H + h) * D;
#pragma unroll
        for (int jd = 0; jd < 4; ++jd)
            ob[jd * 16 + l16] = acc[jd][r] * inv;
    }
}

// ---------------------------------------------------------------------------
// Fallback (R0 kernel, verified): used only if ws is too small.
// ---------------------------------------------------------------------------
__device__ __forceinline__ void stage_rm_fb(const float* __restrict__ src,
                                            char* hi_t, char* lo_t, float scale) {
    const int tid = threadIdx.x;
    const int row = tid >> 2;
    const int c0  = (tid & 3) << 4;
    const float* p = src + row * 64 + c0;
    f32x4 vv[4] = { *(const f32x4*)(p), *(const f32x4*)(p + 4),
                    *(const f32x4*)(p + 8), *(const f32x4*)(p + 12) };
    bf16x8 h2[2], l2[2];
#pragma unroll
    for (int e = 0; e < 16; ++e) {
        float x = vv[e >> 2][e & 3] * scale;
        unsigned short hb = f2bf(x);
        unsigned short lb = f2bf(x - bf2f(hb));
        h2[e >> 3][e & 7] = (short)hb;
        l2[e >> 3][e & 7] = (short)lb;
    }
#pragma unroll
    for (int gi = 0; gi < 2; ++gi) {
        int off = swz_off(row, c0 + gi * 8);
        *(bf16x8*)(hi_t + off) = h2[gi];
        *(bf16x8*)(lo_t + off) = l2[gi];
    }
}
__device__ __forceinline__ void stage_tr_fb(const float* __restrict__ src,
                                            char* hi_t, char* lo_t) {
    const int tid = threadIdx.x;
    const int t  = tid >> 2;
    const int c0 = (tid & 3) << 4;
    const float* p = src + t * 64 + c0;
    f32x4 vv[4] = { *(const f32x4*)(p), *(const f32x4*)(p + 4),
                    *(const f32x4*)(p + 8), *(const f32x4*)(p + 12) };
#pragma unroll
    for (int e = 0; e < 16; ++e) {
        float x = vv[e >> 2][e & 3];
        unsigned short hb = f2bf(x);
        unsigned short lb = f2bf(x - bf2f(hb));
        int d = c0 + e;
        int off = swz_off(d, 0) + 0;
        off = (d * 128 + t * 2) ^ ((d & 7) << 4);
        *(unsigned short*)(hi_t + off) = hb;
        *(unsigned short*)(lo_t + off) = lb;
    }
}
__global__ __launch_bounds__(256) void bigbird_kernel_fb(
    const float* __restrict__ Q, const float* __restrict__ K,
    const float* __restrict__ V, const float* __restrict__ M,
    float* __restrict__ Out) {
    constexpr int H = 16, F = 1024, T = 1024, D = 64;
    __shared__ char kq_hi[8192];
    __shared__ char kq_lo[8192];
    __shared__ char vt_hi[8192];
    __shared__ char vt_lo[8192];
    __shared__ char p_sm[8192];
    __shared__ int flags[16];
    const int bid = blockIdx.x;
    const int fb  = bid & 15;
    const int h   = (bid >> 4) & 15;
    const int b   = bid >> 8;
    const int tid  = threadIdx.x;
    const int lane = tid & 63;
    const int w    = tid >> 6;
    const int g    = lane >> 4;
    const int l16  = lane & 15;
    if (tid < 16)
        flags[tid] = (M[(h * 1024 + fb * 64) * 1024 + tid * 64] > 0.5f) ? 1 : 0;
    const float* qb = Q + ((size_t)(b * H + h) * F + fb * 64) * D;
    stage_rm_fb(qb, kq_hi, kq_lo, 0.125f);
    __syncthreads();
    bf16x8 qh[2], ql[2];
#pragma unroll
    for (int kk = 0; kk < 2; ++kk) {
        qh[kk] = ld_frag(kq_hi, w * 16 + l16, kk * 32 + g * 8);
        ql[kk] = ld_frag(kq_lo, w * 16 + l16, kk * 32 + g * 8);
    }
    f32x4 acc[4];
    float m_r[4], l_r[4];
#pragma unroll
    for (int j = 0; j < 4; ++j) acc[j] = f32x4{0.f, 0.f, 0.f, 0.f};
#pragma unroll
    for (int r = 0; r < 4; ++r) { m_r[r] = -1e30f; l_r[r] = 0.f; }
    const float* kb = K + (size_t)(b * H + h) * T * D;
    const float* vb = V + (size_t)(b * H + h) * T * D;
    for (int tb = 0; tb < 16; ++tb) {
        if (!flags[tb]) continue;
        __syncthreads();
        stage_rm_fb(kb + tb * 64 * D, kq_hi, kq_lo, 1.0f);
        stage_tr_fb(vb + tb * 64 * D, vt_hi, vt_lo);
        __syncthreads();
        f32x4 s[4];
#pragma unroll
        for (int j = 0; j < 4; ++j) {
            s[j] = f32x4{0.f, 0.f, 0.f, 0.f};
#pragma unroll
            for (int kk = 0; kk < 2; ++kk) {
                bf16x8 bhf = ld_frag(kq_hi, j * 16 + l16, kk * 32 + g * 8);
                bf16x8 blf = ld_frag(kq_lo, j * 16 + l16, kk * 32 + g * 8);
                s[j] = MFMA(qh[kk], bhf, s[j]);
                s[j] = MFMA(qh[kk], blf, s[j]);
                s[j] = MFMA(ql[kk], bhf, s[j]);
            }
        }
        float rmax[4];
#pragma unroll
        for (int r = 0; r < 4; ++r)
            rmax[r] = fmaxf(fmaxf(s[0][r], s[1][r]), fmaxf(s[2][r], s[3][r]));
#pragma unroll
        for (int off = 1; off < 16; off <<= 1)
#pragma unroll
            for (int r = 0; r < 4; ++r)
                rmax[r] = fmaxf(rmax[r], __shfl_xor(rmax[r], off, 64));
        float alpha[4], psum[4];
#pragma unroll
        for (int r = 0; r < 4; ++r) {
            float mn = fmaxf(m_r[r], rmax[r]);
            alpha[r] = __expf(m_r[r] - mn);
            m_r[r]   = mn;
            psum[r]  = 0.f;
        }
#pragma unroll
        for (int j = 0; j < 4; ++j)
#pragma unroll
            for (int r = 0; r < 4; ++r) {
                float pe = __expf(s[j][r] - m_r[r]);
                s[j][r] = pe;
                psum[r] += pe;
            }
#pragma unroll
        for (int off = 1; off < 16; off <<= 1)
#pragma unroll
            for (int r = 0; r < 4; ++r)
                psum[r] += __shfl_xor(psum[r], off, 64);
#pragma unroll
        for (int r = 0; r < 4; ++r)
            l_r[r] = l_r[r] * alpha[r] + psum[r];
#pragma unroll
        for (int j = 0; j < 4; ++j)
#pragma unroll
            for (int r = 0; r < 4; ++r)
                acc[j][r] *= alpha[r];
#pragma unroll
        for (int j = 0; j < 4; ++j)
#pragma unroll
            for (int r = 0; r < 4; ++r) {
                int row = w * 16 + g * 4 + r;
                *(unsigned short*)(p_sm + swz_off(row, j * 16 + l16)) = f2bf(s[j][r]);
            }
        __syncthreads();
#pragma unroll
        for (int kk = 0; kk < 2; ++kk) {
            bf16x8 pa = ld_frag(p_sm, w * 16 + l16, kk * 32 + g * 8);
#pragma unroll
            for (int jd = 0; jd < 4; ++jd) {
                bf16x8 vh = ld_frag(vt_hi, jd * 16 + l16, kk * 32 + g * 8);
                bf16x8 vl = ld_frag(vt_lo, jd * 16 + l16, kk * 32 + g * 8);
                acc[jd] = MFMA(pa, vh, acc[jd]);
                acc[jd] = MFMA(pa, vl, acc[jd]);
            }
        }
    }
#pragma unroll
    for (int r = 0; r < 4; ++r) {
        float inv = 1.0f / l_r[r];
        int f = fb * 64 + w * 16 + g * 4 + r;
        float* ob = Out + ((size_t)(b * F + f) * H + h) * D;
#pragma unroll
        for (int jd = 0; jd < 4; ++jd)
            ob[jd * 16 + l16] = acc[jd][r] * inv;
    }
}

extern "C" void kernel_launch(void* const* d_in, const int* in_sizes, int n_in,
                              void* d_out, int out_size, void* d_ws, size_t ws_size,
                              hipStream_t stream) {
    const float* q = (const float*)d_in[0];
    const float* k = (const float*)d_in[1];
    const float* v = (const float*)d_in[2];
    const float* m = (const float*)d_in[3];
    float* out = (float*)d_out;
    if (ws_size >= WS_NEED) {
        bigbird_prepass<<<dim3(512), dim3(256), 0, stream>>>(k, v, (char*)d_ws);
        bigbird_main<<<dim3(512), dim3(256), 0, stream>>>(q, m, (const char*)d_ws, out);
    } else {
        bigbird_kernel_fb<<<dim3(512), dim3(256), 0, stream>>>(q, k, v, m, out);
    }
}

// Round 3
// 38.997 us; speedup vs baseline: 1.8059x; 1.5545x over previous
//
#include <hip/hip_runtime.h>

typedef __attribute__((ext_vector_type(4))) float f32x4;
typedef __attribute__((ext_vector_type(8))) short bf16x8;
typedef _Float16 f16x8 __attribute__((ext_vector_type(8)));

#define MFMA16(a, b, c) __builtin_amdgcn_mfma_f32_16x16x32_f16((a), (b), (c), 0, 0, 0)
#define MFMABF(a, b, c) __builtin_amdgcn_mfma_f32_16x16x32_bf16((a), (b), (c), 0, 0, 0)

constexpr size_t TILE_FRAG_BYTES = 8192;               // 64x64 fp16, frag-major
constexpr size_t NTILES = 512;                         // B*H*16
constexpr size_t ARR_S  = NTILES * TILE_FRAG_BYTES;    // 4 MiB (K or V array)
constexpr size_t WS_NEED = 2 * ARR_S;                  // Kfrag + Vfrag

// Swizzled byte offset inside an 8 KiB 64x64 2-byte-elem LDS tile.
__device__ __forceinline__ int swz_off(int row, int col) {
    return (row * 128 + col * 2) ^ ((row & 7) << 4);
}
__device__ __forceinline__ f16x8 ld_frag16(const char* tile, int row, int col) {
    return *(const f16x8*)(tile + swz_off(row, col));
}

// ---------------------------------------------------------------------------
// Pre-pass: convert K -> fp16 fragment-major tiles, V -> transposed fp16
// fragment-major tiles. Frag f=(j*2+kk): element [lane][e] =
//   K[j*16+(lane&15)][kk*32+(lane>>4)*8+e]        (B-frag for QK^T)
//   V[kk*32+(lane>>4)*8+e][j*16+(lane&15)]        (B-frag for PV, V^T)
// A wave's fragment load in the main kernel is then 1 KiB contiguous.
// ---------------------------------------------------------------------------
__global__ __launch_bounds__(256) void bigbird_prepass(
    const float* __restrict__ K, const float* __restrict__ V,
    char* __restrict__ ws) {
    __shared__ float kf[64][66];
    __shared__ float vf[64][66];
    const int tile = blockIdx.x;
    const int tid  = threadIdx.x;
    const int row  = tid >> 2;
    const int c0   = (tid & 3) << 4;
    const float* Kt = K + (size_t)tile * 4096;
    const float* Vt = V + (size_t)tile * 4096;
    {
        const float* p = Kt + row * 64 + c0;
        f32x4 a = *(const f32x4*)p, bq = *(const f32x4*)(p + 4),
              c = *(const f32x4*)(p + 8), d = *(const f32x4*)(p + 12);
#pragma unroll
        for (int e = 0; e < 4; ++e) {
            kf[row][c0 + e] = a[e];      kf[row][c0 + 4 + e] = bq[e];
            kf[row][c0 + 8 + e] = c[e];  kf[row][c0 + 12 + e] = d[e];
        }
        const float* q = Vt + row * 64 + c0;
        f32x4 e0 = *(const f32x4*)q, e1 = *(const f32x4*)(q + 4),
              e2 = *(const f32x4*)(q + 8), e3 = *(const f32x4*)(q + 12);
#pragma unroll
        for (int e = 0; e < 4; ++e) {
            vf[row][c0 + e] = e0[e];     vf[row][c0 + 4 + e] = e1[e];
            vf[row][c0 + 8 + e] = e2[e]; vf[row][c0 + 12 + e] = e3[e];
        }
    }
    __syncthreads();
    f16x8* Ko = (f16x8*)(ws + (size_t)tile * TILE_FRAG_BYTES);
    f16x8* Vo = (f16x8*)(ws + ARR_S + (size_t)tile * TILE_FRAG_BYTES);
#pragma unroll
    for (int t = 0; t < 2; ++t) {
        int s = tid + t * 256;
        int f = s >> 6, lane = s & 63;
        int j = f >> 1, kk = f & 1;
        int l16 = lane & 15, g = lane >> 4;
        f16x8 kv, vv;
#pragma unroll
        for (int e = 0; e < 8; ++e) {
            kv[e] = (_Float16)kf[j * 16 + l16][kk * 32 + g * 8 + e];
            vv[e] = (_Float16)vf[kk * 32 + g * 8 + e][j * 16 + l16];
        }
        Ko[s] = kv;
        Vo[s] = vv;
    }
}

// ---------------------------------------------------------------------------
// Main: one WG per (b,h,row-block); waves free-run (no barriers in loop).
// Fragments stream straight from frag-major global (L2-resident per XCD).
// ---------------------------------------------------------------------------
__global__ __launch_bounds__(256) void bigbird_main(
    const float* __restrict__ Q, const float* __restrict__ M,
    const char* __restrict__ ws, float* __restrict__ Out) {
    constexpr int H = 16, F = 1024, D = 64;

    __shared__ char p_sm[8192];
    __shared__ int flags[16];
    __shared__ int list[16];
    __shared__ int ncnt;

    // XCD-grouped remap: all 16 row-blocks of one (b,h) on one XCD.
    const int i0  = blockIdx.x;
    const int xcd = i0 & 7;
    const int q0  = i0 >> 3;
    const int grp = xcd * 4 + (q0 >> 4);   // 0..31 == b*16+h
    const int fb  = q0 & 15;
    const int b   = grp >> 4;
    const int h   = grp & 15;
    const int bh  = grp;

    const int tid  = threadIdx.x;
    const int lane = tid & 63;
    const int w    = tid >> 6;
    const int g    = lane >> 4;
    const int l16  = lane & 15;

    if (tid < 16)
        flags[tid] = (M[((size_t)(h * 1024 + fb * 64)) * 1024 + tid * 64] > 0.5f) ? 1 : 0;

    // Q A-fragments (fp16, scaled by 1/sqrt(64)=0.125) straight from global.
    f16x8 qf[2];
    {
        const float* qr = Q + ((size_t)bh * F + fb * 64 + w * 16 + l16) * D;
#pragma unroll
        for (int kk = 0; kk < 2; ++kk) {
            const float* p = qr + kk * 32 + g * 8;
            f32x4 a = *(const f32x4*)p;
            f32x4 c = *(const f32x4*)(p + 4);
#pragma unroll
            for (int e = 0; e < 8; ++e)
                qf[kk][e] = (_Float16)((e < 4 ? a[e] : c[e - 4]) * 0.125f);
        }
    }
    __syncthreads();
    if (tid == 0) {
        int nn = 0;
        for (int t = 0; t < 16; ++t)
            if (flags[t]) list[nn++] = t;
        ncnt = nn;
    }
    __syncthreads();
    const int n = ncnt;

    f32x4 acc[4];
    float m_r[4], l_r[4];
#pragma unroll
    for (int j = 0; j < 4; ++j) acc[j] = f32x4{0.f, 0.f, 0.f, 0.f};
#pragma unroll
    for (int r = 0; r < 4; ++r) { m_r[r] = -1e30f; l_r[r] = 0.f; }

    const f16x8* Kbase = (const f16x8*)ws + (size_t)bh * 16 * 512;
    const f16x8* Vbase = (const f16x8*)(ws + ARR_S) + (size_t)bh * 16 * 512;

    for (int i = 0; i < n; ++i) {
        const int tb = list[i];
        const f16x8* Kf = Kbase + (size_t)tb * 512;
        const f16x8* Vf = Vbase + (size_t)tb * 512;

        // All 16 fragment loads issued together (coalesced 1 KiB each).
        f16x8 kfr[4][2], vfr[4][2];
#pragma unroll
        for (int j = 0; j < 4; ++j)
#pragma unroll
            for (int kk = 0; kk < 2; ++kk) {
                kfr[j][kk] = Kf[(j * 2 + kk) * 64 + lane];
                vfr[j][kk] = Vf[(j * 2 + kk) * 64 + lane];
            }

        // S = Q K^T  (fp16 single-term)
        f32x4 s[4];
#pragma unroll
        for (int j = 0; j < 4; ++j) {
            s[j] = f32x4{0.f, 0.f, 0.f, 0.f};
#pragma unroll
            for (int kk = 0; kk < 2; ++kk)
                s[j] = MFMA16(qf[kk], kfr[j][kk], s[j]);
        }

        // Online softmax. C-layout: lane holds rows g*4+r (+w*16), col j*16+l16.
        float rmax[4];
#pragma unroll
        for (int r = 0; r < 4; ++r)
            rmax[r] = fmaxf(fmaxf(s[0][r], s[1][r]), fmaxf(s[2][r], s[3][r]));
#pragma unroll
        for (int off = 1; off < 16; off <<= 1)
#pragma unroll
            for (int r = 0; r < 4; ++r)
                rmax[r] = fmaxf(rmax[r], __shfl_xor(rmax[r], off, 64));
        float alpha[4], psum[4];
#pragma unroll
        for (int r = 0; r < 4; ++r) {
            float mn = fmaxf(m_r[r], rmax[r]);
            alpha[r] = __expf(m_r[r] - mn);
            m_r[r]   = mn;
            psum[r]  = 0.f;
        }
#pragma unroll
        for (int j = 0; j < 4; ++j)
#pragma unroll
            for (int r = 0; r < 4; ++r) {
                float pe = __expf(s[j][r] - m_r[r]);
                s[j][r] = pe;
                psum[r] += pe;
            }
#pragma unroll
        for (int off = 1; off < 16; off <<= 1)
#pragma unroll
            for (int r = 0; r < 4; ++r)
                psum[r] += __shfl_xor(psum[r], off, 64);
#pragma unroll
        for (int r = 0; r < 4; ++r)
            l_r[r] = l_r[r] * alpha[r] + psum[r];
#pragma unroll
        for (int j = 0; j < 4; ++j)
#pragma unroll
            for (int r = 0; r < 4; ++r)
                acc[j][r] *= alpha[r];

        // P (fp16) -> wave-private LDS strip to reshape C-layout -> A-frag.
#pragma unroll
        for (int j = 0; j < 4; ++j)
#pragma unroll
            for (int r = 0; r < 4; ++r) {
                int row = w * 16 + g * 4 + r;
                *(_Float16*)(p_sm + swz_off(row, j * 16 + l16)) = (_Float16)s[j][r];
            }
        // Wave-local wait on own ds_writes; fence so MFMA isn't hoisted above.
        asm volatile("s_waitcnt lgkmcnt(0)" ::: "memory");
        __builtin_amdgcn_sched_barrier(0);

        // O += P * V
#pragma unroll
        for (int kk = 0; kk < 2; ++kk) {
            f16x8 pa = ld_frag16(p_sm, w * 16 + l16, kk * 32 + g * 8);
#pragma unroll
            for (int jd = 0; jd < 4; ++jd)
                acc[jd] = MFMA16(pa, vfr[jd][kk], acc[jd]);
        }
    }

    // Epilogue: normalize, write [B, F, H, D].
#pragma unroll
    for (int r = 0; r < 4; ++r) {
        float inv = 1.0f / l_r[r];
        int f = fb * 64 + w * 16 + g * 4 + r;
        float* ob = Out + ((size_t)(b * F + f) * H + h) * D;
#pragma unroll
        for (int jd = 0; jd < 4; ++jd)
            ob[jd * 16 + l16] = acc[jd][r] * inv;
    }
}

// ---------------------------------------------------------------------------
// Fallback (R0 kernel, verified): used only if ws is too small.
// ---------------------------------------------------------------------------
__device__ __forceinline__ unsigned short f2bf(float x) {
    unsigned u = __builtin_bit_cast(unsigned, x);
    unsigned r = u + 0x7fffu + ((u >> 16) & 1u);
    return (unsigned short)(r >> 16);
}
__device__ __forceinline__ float bf2f(unsigned short h) {
    return __builtin_bit_cast(float, (unsigned)h << 16);
}
__device__ __forceinline__ bf16x8 ld_fragb(const char* tile, int row, int col) {
    return *(const bf16x8*)(tile + swz_off(row, col));
}
__device__ __forceinline__ void stage_rm_fb(const float* __restrict__ src,
                                            char* hi_t, char* lo_t, float scale) {
    const int tid = threadIdx.x;
    const int row = tid >> 2;
    const int c0  = (tid & 3) << 4;
    const float* p = src + row * 64 + c0;
    f32x4 vv[4] = { *(const f32x4*)(p), *(const f32x4*)(p + 4),
                    *(const f32x4*)(p + 8), *(const f32x4*)(p + 12) };
    bf16x8 h2[2], l2[2];
#pragma unroll
    for (int e = 0; e < 16; ++e) {
        float x = vv[e >> 2][e & 3] * scale;
        unsigned short hb = f2bf(x);
        unsigned short lb = f2bf(x - bf2f(hb));
        h2[e >> 3][e & 7] = (short)hb;
        l2[e >> 3][e & 7] = (short)lb;
    }
#pragma unroll
    for (int gi = 0; gi < 2; ++gi) {
        int off = swz_off(row, c0 + gi * 8);
        *(bf16x8*)(hi_t + off) = h2[gi];
        *(bf16x8*)(lo_t + off) = l2[gi];
    }
}
__device__ __forceinline__ void stage_tr_fb(const float* __restrict__ src,
                                            char* hi_t, char* lo_t) {
    const int tid = threadIdx.x;
    const int t  = tid >> 2;
    const int c0 = (tid & 3) << 4;
    const float* p = src + t * 64 + c0;
    f32x4 vv[4] = { *(const f32x4*)(p), *(const f32x4*)(p + 4),
                    *(const f32x4*)(p + 8), *(const f32x4*)(p + 12) };
#pragma unroll
    for (int e = 0; e < 16; ++e) {
        float x = vv[e >> 2][e & 3];
        unsigned short hb = f2bf(x);
        unsigned short lb = f2bf(x - bf2f(hb));
        int d = c0 + e;
        int off = (d * 128 + t * 2) ^ ((d & 7) << 4);
        *(unsigned short*)(hi_t + off) = hb;
        *(unsigned short*)(lo_t + off) = lb;
    }
}
__global__ __launch_bounds__(256) void bigbird_kernel_fb(
    const float* __restrict__ Q, const float* __restrict__ K,
    const float* __restrict__ V, const float* __restrict__ M,
    float* __restrict__ Out) {
    constexpr int H = 16, F = 1024, D = 64;
    __shared__ char kq_hi[8192];
    __shared__ char kq_lo[8192];
    __shared__ char vt_hi[8192];
    __shared__ char vt_lo[8192];
    __shared__ char p_sm[8192];
    __shared__ int flags[16];
    const int bid = blockIdx.x;
    const int fb  = bid & 15;
    const int h   = (bid >> 4) & 15;
    const int b   = bid >> 8;
    const int tid  = threadIdx.x;
    const int lane = tid & 63;
    const int w    = tid >> 6;
    const int g    = lane >> 4;
    const int l16  = lane & 15;
    if (tid < 16)
        flags[tid] = (M[(h * 1024 + fb * 64) * 1024 + tid * 64] > 0.5f) ? 1 : 0;
    const float* qb = Q + ((size_t)(b * H + h) * F + fb * 64) * D;
    stage_rm_fb(qb, kq_hi, kq_lo, 0.125f);
    __syncthreads();
    bf16x8 qh[2], ql[2];
#pragma unroll
    for (int kk = 0; kk < 2; ++kk) {
        qh[kk] = ld_fragb(kq_hi, w * 16 + l16, kk * 32 + g * 8);
        ql[kk] = ld_fragb(kq_lo, w * 16 + l16, kk * 32 + g * 8);
    }
    f32x4 acc[4];
    float m_r[4], l_r[4];
#pragma unroll
    for (int j = 0; j < 4; ++j) acc[j] = f32x4{0.f, 0.f, 0.f, 0.f};
#pragma unroll
    for (int r = 0; r < 4; ++r) { m_r[r] = -1e30f; l_r[r] = 0.f; }
    const float* kb = K + (size_t)(b * H + h) * 1024 * D;
    const float* vb = V + (size_t)(b * H + h) * 1024 * D;
    for (int tb = 0; tb < 16; ++tb) {
        if (!flags[tb]) continue;
        __syncthreads();
        stage_rm_fb(kb + tb * 64 * D, kq_hi, kq_lo, 1.0f);
        stage_tr_fb(vb + tb * 64 * D, vt_hi, vt_lo);
        __syncthreads();
        f32x4 s[4];
#pragma unroll
        for (int j = 0; j < 4; ++j) {
            s[j] = f32x4{0.f, 0.f, 0.f, 0.f};
#pragma unroll
            for (int kk = 0; kk < 2; ++kk) {
                bf16x8 bhf = ld_fragb(kq_hi, j * 16 + l16, kk * 32 + g * 8);
                bf16x8 blf = ld_fragb(kq_lo, j * 16 + l16, kk * 32 + g * 8);
                s[j] = MFMABF(qh[kk], bhf, s[j]);
                s[j] = MFMABF(qh[kk], blf, s[j]);
                s[j] = MFMABF(ql[kk], bhf, s[j]);
            }
        }
        float rmax[4];
#pragma unroll
        for (int r = 0; r < 4; ++r)
            rmax[r] = fmaxf(fmaxf(s[0][r], s[1][r]), fmaxf(s[2][r], s[3][r]));
#pragma unroll
        for (int off = 1; off < 16; off <<= 1)
#pragma unroll
            for (int r = 0; r < 4; ++r)
                rmax[r] = fmaxf(rmax[r], __shfl_xor(rmax[r], off, 64));
        float alpha[4], psum[4];
#pragma unroll
        for (int r = 0; r < 4; ++r) {
            float mn = fmaxf(m_r[r], rmax[r]);
            alpha[r] = __expf(m_r[r] - mn);
            m_r[r]   = mn;
            psum[r]  = 0.f;
        }
#pragma unroll
        for (int j = 0; j < 4; ++j)
#pragma unroll
            for (int r = 0; r < 4; ++r) {
                float pe = __expf(s[j][r] - m_r[r]);
                s[j][r] = pe;
                psum[r] += pe;
            }
#pragma unroll
        for (int off = 1; off < 16; off <<= 1)
#pragma unroll
            for (int r = 0; r < 4; ++r)
                psum[r] += __shfl_xor(psum[r], off, 64);
#pragma unroll
        for (int r = 0; r < 4; ++r)
            l_r[r] = l_r[r] * alpha[r] + psum[r];
#pragma unroll
        for (int j = 0; j < 4; ++j)
#pragma unroll
            for (int r = 0; r < 4; ++r)
                acc[j][r] *= alpha[r];
#pragma unroll
        for (int j = 0; j < 4; ++j)
#pragma unroll
            for (int r = 0; r < 4; ++r) {
                int row = w * 16 + g * 4 + r;
                *(unsigned short*)(p_sm + swz_off(row, j * 16 + l16)) = f2bf(s[j][r]);
            }
        __syncthreads();
#pragma unroll
        for (int kk = 0; kk < 2; ++kk) {
            bf16x8 pa = ld_fragb(p_sm, w * 16 + l16, kk * 32 + g * 8);
#pragma unroll
            for (int jd = 0; jd < 4; ++jd) {
                bf16x8 vh = ld_fragb(vt_hi, jd * 16 + l16, kk * 32 + g * 8);
                bf16x8 vl = ld_fragb(vt_lo, jd * 16 + l16, kk * 32 + g * 8);
                acc[jd] = MFMABF(pa, vh, acc[jd]);
                acc[jd] = MFMABF(pa, vl, acc[jd]);
            }
        }
    }
#pragma unroll
    for (int r = 0; r < 4; ++r) {
        float inv = 1.0f / l_r[r];
        int f = fb * 64 + w * 16 + g * 4 + r;
        float* ob = Out + ((size_t)(b * F + f) * H + h) * D;
#pragma unroll
        for (int jd = 0; jd < 4; ++jd)
            ob[jd * 16 + l16] = acc[jd][r] * inv;
    }
}

extern "C" void kernel_launch(void* const* d_in, const int* in_sizes, int n_in,
                              void* d_out, int out_size, void* d_ws, size_t ws_size,
                              hipStream_t stream) {
    const float* q = (const float*)d_in[0];
    const float* k = (const float*)d_in[1];
    const float* v = (const float*)d_in[2];
    const float* m = (const float*)d_in[3];
    float* out = (float*)d_out;
    if (ws_size >= WS_NEED) {
        bigbird_prepass<<<dim3(512), dim3(256), 0, stream>>>(k, v, (char*)d_ws);
        bigbird_main<<<dim3(512), dim3(256), 0, stream>>>(q, m, (const char*)d_ws, out);
    } else {
        bigbird_kernel_fb<<<dim3(512), dim3(256), 0, stream>>>(q, k, v, m, out);
    }
}